// Round 4
// baseline (305.967 us; speedup 1.0000x reference)
//
#include <hip/hip_runtime.h>
#include <hip/hip_cooperative_groups.h>
#include <math.h>

namespace cg = cooperative_groups;

#define BINS 128

__device__ __forceinline__ unsigned mapf(float f) {
    unsigned u = __float_as_uint(f);
    return (u & 0x80000000u) ? ~u : (u | 0x80000000u);
}
__device__ __forceinline__ float unmapf(unsigned m) {
    unsigned u = (m & 0x80000000u) ? (m & 0x7FFFFFFFu) : ~m;
    return __uint_as_float(u);
}
__device__ __forceinline__ float sel4(float g0, float g1, float g2, float g3, int k) {
    float a = (k & 1) ? g1 : g0;
    float b = (k & 1) ? g3 : g2;
    return (k & 2) ? b : a;
}

// ================= gate recompute macro (shared by fused + fallback-free design) ==========
// Decodes float4 index i of x (B,C,D,H,W), computes 4 gated products from the
// 4^3 gate in ls[] using per-lane w-axis constants.
#define COMPUTE_PRODUCTS(i, p0, p1, p2, p3)                                           \
    {                                                                                 \
        float4 xv = x4[i];                                                            \
        const int h6 = ((i) >> 4) & 63;                                               \
        const int d6 = ((i) >> 10) & 63;                                              \
        const int bb = (i) >> 22;                                                     \
        const int hl = llo[h6], dl = llo[d6];                                         \
        const float fh = lwt[h6], fd = lwt[d6];                                       \
        const int hh = min(hl + 1, 3), dh = min(dl + 1, 3);                           \
        const float* sb = ls + bb * 64;                                               \
        const float w00 = (1.f - fd) * (1.f - fh), w01 = (1.f - fd) * fh;             \
        const float w10 = fd * (1.f - fh), w11 = fd * fh;                             \
        const int i00 = dl * 16 + hl * 4, i01 = dl * 16 + hh * 4;                     \
        const int i10 = dh * 16 + hl * 4, i11 = dh * 16 + hh * 4;                     \
        const float g0 = w00 * sb[i00 + 0] + w01 * sb[i01 + 0] + w10 * sb[i10 + 0] + w11 * sb[i11 + 0]; \
        const float g1 = w00 * sb[i00 + 1] + w01 * sb[i01 + 1] + w10 * sb[i10 + 1] + w11 * sb[i11 + 1]; \
        const float g2 = w00 * sb[i00 + 2] + w01 * sb[i01 + 2] + w10 * sb[i10 + 2] + w11 * sb[i11 + 2]; \
        const float g3 = w00 * sb[i00 + 3] + w01 * sb[i01 + 3] + w10 * sb[i10 + 3] + w11 * sb[i11 + 3]; \
        float glo, ghi, sv;                                                           \
        glo = sel4(g0, g1, g2, g3, wl0); ghi = sel4(g0, g1, g2, g3, wh0);             \
        sv = glo + fw0 * (ghi - glo); p0 = xv.x * sv;                                 \
        glo = sel4(g0, g1, g2, g3, wl1); ghi = sel4(g0, g1, g2, g3, wh1);             \
        sv = glo + fw1 * (ghi - glo); p1 = xv.y * sv;                                 \
        glo = sel4(g0, g1, g2, g3, wl2); ghi = sel4(g0, g1, g2, g3, wh2);             \
        sv = glo + fw2 * (ghi - glo); p2 = xv.z * sv;                                 \
        glo = sel4(g0, g1, g2, g3, wl3); ghi = sel4(g0, g1, g2, g3, wh3);             \
        sv = glo + fw3 * (ghi - glo); p3 = xv.w * sv;                                 \
    }

// ================================================================================
// Fused cooperative kernel. ws layout (floats):
// [0,16384) pp pool partials [slab*8+part][16] ; [16384,17408) hs [2][8][64]
// [17408,17410) mm ; [17424,17552) ghist
// ================================================================================
__global__ __launch_bounds__(256, 4) void fused_kernel(const float* __restrict__ x,
                                                       const float* __restrict__ w1,
                                                       const float* __restrict__ w2,
                                                       float* __restrict__ out,
                                                       float* __restrict__ ws,
                                                       int G) {
    cg::grid_group grid = cg::this_grid();

    float* pp       = ws;
    float* hs       = ws + 16384;
    unsigned* mm    = (unsigned*)(ws + 17408);
    unsigned* ghist = (unsigned*)(ws + 17424);

    const int t    = threadIdx.x;
    const int bid  = blockIdx.x;
    const int lane = t & 63;
    const int wave = t >> 6;

    __shared__ float red[64];
    __shared__ float ls[128];
    __shared__ int   llo[64];
    __shared__ float lwt[64];
    __shared__ unsigned lh[BINS];

    // ---------------- P0: pool partials (1024 slab-parts, grid-stride) ----------------
    if (bid == 0) {
        if (t == 0) { mm[0] = 0xFFFFFFFFu; mm[1] = 0u; }
        if (t >= 64 && t < 192) ghist[t - 64] = 0u;
    }
    for (int sb = bid; sb < 1024; sb += G) {
        const float4* xb = (const float4*)x + (size_t)sb * 8192;
        float a0 = 0.f, a1 = 0.f, a2 = 0.f, a3 = 0.f;
        #pragma unroll 2
        for (int n = 0; n < 32; n += 4) {
            float4 v0 = xb[(n + 0) * 256 + t]; a0 += (v0.x + v0.y) + (v0.z + v0.w);
            float4 v1 = xb[(n + 1) * 256 + t]; a1 += (v1.x + v1.y) + (v1.z + v1.w);
            float4 v2 = xb[(n + 2) * 256 + t]; a2 += (v2.x + v2.y) + (v2.z + v2.w);
            float4 v3 = xb[(n + 3) * 256 + t]; a3 += (v3.x + v3.y) + (v3.z + v3.w);
        }
        // ph = n&3 -> a0..a3 ; pw = lane bits {2,3} ; reduce lane bits {0,1,4,5}
        #pragma unroll
        for (int m = 0; m < 4; ++m) {
            const int msk = (m == 0) ? 1 : (m == 1) ? 2 : (m == 2) ? 16 : 32;
            a0 += __shfl_xor(a0, msk); a1 += __shfl_xor(a1, msk);
            a2 += __shfl_xor(a2, msk); a3 += __shfl_xor(a3, msk);
        }
        __syncthreads();
        if (lane < 16 && (lane & 3) == 0) {
            const int pw = lane >> 2;
            red[(0 * 4 + pw) * 4 + wave] = a0;
            red[(1 * 4 + pw) * 4 + wave] = a1;
            red[(2 * 4 + pw) * 4 + wave] = a2;
            red[(3 * 4 + pw) * 4 + wave] = a3;
        }
        __syncthreads();
        if (t < 16)
            pp[sb * 16 + t] = red[t * 4 + 0] + red[t * 4 + 1] + red[t * 4 + 2] + red[t * 4 + 3];
    }
    grid.sync();

    // ---------------- P1: w1 conv + InstanceNorm + GELU (16 blocks, wave 0) ----------------
    if (bid < 16 && t < 64) {
        const int b = bid >> 3, cm = bid & 7, sp = t;
        const int off = (sp >> 4) * 32 + (sp & 15);
        const float* w1r = w1 + cm * 64;
        const float* ppb = pp + b * 64 * 128;
        float h = 0.f;
        for (int c = 0; c < 64; ++c)
            h += w1r[c] * (ppb[c * 128 + off] + ppb[c * 128 + 16 + off]);
        h *= (1.0f / 4096.0f);

        float s1 = h;
        #pragma unroll
        for (int m = 1; m <= 32; m <<= 1) s1 += __shfl_xor(s1, m);
        const float mu = s1 * (1.0f / 64.0f);
        float d = h - mu;
        float s2 = d * d;
        #pragma unroll
        for (int m = 1; m <= 32; m <<= 1) s2 += __shfl_xor(s2, m);
        const float var = s2 * (1.0f / 64.0f);
        const float hn = d / sqrtf(var + 1e-5f);
        hs[bid * 64 + sp] = 0.5f * hn * (1.0f + erff(hn * 0.70710678118654752440f));
    }
    grid.sync();

    // ---------------- per-block prep: gate + lerp tables ----------------
    if (t < 128) {
        const int b = t >> 6, sp = t & 63;
        float acc = 0.f;
        #pragma unroll
        for (int c = 0; c < 8; ++c) acc += w2[c] * hs[(b * 8 + c) * 64 + sp];
        ls[t] = 1.0f / (1.0f + expf(-acc));
    }
    if (t < 64) {
        float coord = ((float)t + 0.5f) * 0.0625f - 0.5f;
        coord = fminf(fmaxf(coord, 0.0f), 3.0f);
        int lo = (int)floorf(coord);
        llo[t] = lo;
        lwt[t] = coord - (float)lo;
    }
    __syncthreads();

    const int wbase = (lane & 15) * 4;
    const int wl0 = llo[wbase + 0], wl1 = llo[wbase + 1], wl2 = llo[wbase + 2], wl3 = llo[wbase + 3];
    const int wh0 = min(wl0 + 1, 3), wh1 = min(wl1 + 1, 3), wh2 = min(wl2 + 1, 3), wh3 = min(wl3 + 1, 3);
    const float fw0 = lwt[wbase + 0], fw1 = lwt[wbase + 1], fw2 = lwt[wbase + 2], fw3 = lwt[wbase + 3];

    const float4* x4 = (const float4*)x;
    const int stride = G * 256;

    // ---------------- P2: global min/max of x * s ----------------
    {
        float vmin = INFINITY, vmax = -INFINITY;
        #pragma unroll 4
        for (int i = bid * 256 + t; i < 8388608; i += stride) {
            float p0, p1, p2, p3;
            COMPUTE_PRODUCTS(i, p0, p1, p2, p3);
            vmin = fminf(vmin, fminf(fminf(p0, p1), fminf(p2, p3)));
            vmax = fmaxf(vmax, fmaxf(fmaxf(p0, p1), fmaxf(p2, p3)));
        }
        #pragma unroll
        for (int m = 1; m <= 32; m <<= 1) {
            vmin = fminf(vmin, __shfl_xor(vmin, m));
            vmax = fmaxf(vmax, __shfl_xor(vmax, m));
        }
        if ((t & 63) == 0) { red[wave] = vmin; red[4 + wave] = vmax; }
        __syncthreads();
        if (t == 0) {
            float m0 = fminf(fminf(red[0], red[1]), fminf(red[2], red[3]));
            float M0 = fmaxf(fmaxf(red[4], red[5]), fmaxf(red[6], red[7]));
            atomicMin(&mm[0], mapf(m0));
            atomicMax(&mm[1], mapf(M0));
        }
    }
    grid.sync();

    // ---------------- P3: 128-bin histogram ----------------
    {
        if (t < BINS) lh[t] = 0u;
        __syncthreads();
        const float vmin = unmapf(mm[0]);
        const float vmax = unmapf(mm[1]);
        const float inv = 128.0f / (vmax - vmin + 1e-8f);

        #pragma unroll 4
        for (int i = bid * 256 + t; i < 8388608; i += stride) {
            float p0, p1, p2, p3;
            COMPUTE_PRODUCTS(i, p0, p1, p2, p3);
            int i0 = (int)floorf((p0 - vmin) * inv);
            int i1 = (int)floorf((p1 - vmin) * inv);
            int i2 = (int)floorf((p2 - vmin) * inv);
            int i3 = (int)floorf((p3 - vmin) * inv);
            i0 = min(max(i0, 0), BINS - 1);
            i1 = min(max(i1, 0), BINS - 1);
            i2 = min(max(i2, 0), BINS - 1);
            i3 = min(max(i3, 0), BINS - 1);
            unsigned a0 = 1u + (i1 == i0) + (i2 == i0) + (i3 == i0);
            atomicAdd(&lh[i0], a0);
            if (i1 != i0) atomicAdd(&lh[i1], 1u + (i2 == i1) + (i3 == i1));
            if (i2 != i0 && i2 != i1) atomicAdd(&lh[i2], 1u + (i3 == i2));
            if (i3 != i0 && i3 != i1 && i3 != i2) atomicAdd(&lh[i3], 1u);
        }
        __syncthreads();
        if (t < BINS) {
            unsigned sum = lh[t];
            if (sum) atomicAdd(&ghist[t], sum);
        }
    }
    grid.sync();

    // ---------------- P4: entropy (block 0, wave 0) ----------------
    if (bid == 0 && t < 64) {
        float c0 = (float)ghist[t];
        float c1 = (float)ghist[t + 64];
        float s = c0 + c1;
        #pragma unroll
        for (int m = 1; m <= 32; m <<= 1) s += __shfl_xor(s, m);
        const float inv = 1.0f / (s + 1e-10f);
        float p0 = c0 * inv, p1 = c1 * inv;
        float e = p0 * log2f(p0 + 1e-10f) + p1 * log2f(p1 + 1e-10f);
        #pragma unroll
        for (int m = 1; m <= 32; m <<= 1) e += __shfl_xor(e, m);
        if (t == 0) out[0] = -e;
    }
}

// ================================================================================
// Fallback path: the proven R1 six-kernel pipeline (ws layout as in R1).
// ================================================================================
__global__ __launch_bounds__(256) void pool_kernel(const float* __restrict__ x,
                                                   float* __restrict__ p) {
    const int blk = blockIdx.x;
    const int t = threadIdx.x;
    const float4* xb = (const float4*)x + (size_t)blk * 16384;
    float acc0 = 0.f, acc1 = 0.f, acc2 = 0.f, acc3 = 0.f;
    for (int n = 0; n < 64; n += 4) {
        float4 v0 = xb[(n + 0) * 256 + t]; acc0 += (v0.x + v0.y) + (v0.z + v0.w);
        float4 v1 = xb[(n + 1) * 256 + t]; acc1 += (v1.x + v1.y) + (v1.z + v1.w);
        float4 v2 = xb[(n + 2) * 256 + t]; acc2 += (v2.x + v2.y) + (v2.z + v2.w);
        float4 v3 = xb[(n + 3) * 256 + t]; acc3 += (v3.x + v3.y) + (v3.z + v3.w);
    }
    #pragma unroll
    for (int m = 0; m < 4; ++m) {
        int mask = (m == 0) ? 1 : (m == 1) ? 2 : (m == 2) ? 16 : 32;
        acc0 += __shfl_xor(acc0, mask);
        acc1 += __shfl_xor(acc1, mask);
        acc2 += __shfl_xor(acc2, mask);
        acc3 += __shfl_xor(acc3, mask);
    }
    __shared__ float red[64];
    const int lane = t & 63, wave = t >> 6;
    if (lane < 16 && (lane & 3) == 0) {
        const int pw = lane >> 2;
        red[(0 * 4 + pw) * 4 + wave] = acc0;
        red[(1 * 4 + pw) * 4 + wave] = acc1;
        red[(2 * 4 + pw) * 4 + wave] = acc2;
        red[(3 * 4 + pw) * 4 + wave] = acc3;
    }
    __syncthreads();
    if (t < 16)
        p[blk * 16 + t] = (red[t * 4 + 0] + red[t * 4 + 1] + red[t * 4 + 2] + red[t * 4 + 3]) * (1.0f / 4096.0f);
}

__global__ __launch_bounds__(1024) void mid_kernel(const float* __restrict__ p,
                                                   const float* __restrict__ w1,
                                                   const float* __restrict__ w2,
                                                   float* __restrict__ s_out,
                                                   int* __restrict__ lo_tab,
                                                   float* __restrict__ w_tab,
                                                   unsigned* __restrict__ mm,
                                                   unsigned* __restrict__ hist) {
    __shared__ float hs[2 * 8 * 64];
    const int t = threadIdx.x;
    const int b = t >> 9, cm = (t >> 6) & 7, sp = t & 63;
    float h = 0.f;
    const float* pb = p + b * 64 * 64 + sp;
    const float* w1r = w1 + cm * 64;
    for (int c = 0; c < 64; ++c) h += w1r[c] * pb[c * 64];
    float s1 = h;
    #pragma unroll
    for (int m = 1; m <= 32; m <<= 1) s1 += __shfl_xor(s1, m);
    const float mu = s1 * (1.0f / 64.0f);
    float d = h - mu;
    float s2 = d * d;
    #pragma unroll
    for (int m = 1; m <= 32; m <<= 1) s2 += __shfl_xor(s2, m);
    const float var = s2 * (1.0f / 64.0f);
    const float hn = d / sqrtf(var + 1e-5f);
    hs[(b * 8 + cm) * 64 + sp] = 0.5f * hn * (1.0f + erff(hn * 0.70710678118654752440f));
    __syncthreads();
    if (t < 128) {
        const int bb = t >> 6, ss = t & 63;
        float acc = 0.f;
        #pragma unroll
        for (int c = 0; c < 8; ++c) acc += w2[c] * hs[(bb * 8 + c) * 64 + ss];
        s_out[t] = 1.0f / (1.0f + expf(-acc));
    }
    if (t < 64) {
        float coord = ((float)t + 0.5f) * 0.0625f - 0.5f;
        coord = fminf(fmaxf(coord, 0.0f), 3.0f);
        int lo = (int)floorf(coord);
        lo_tab[t] = lo;
        w_tab[t] = coord - (float)lo;
    }
    if (t == 0) { mm[0] = 0xFFFFFFFFu; mm[1] = 0u; }
    if (t >= 128 && t < 256) hist[t - 128] = 0u;
}

__global__ __launch_bounds__(256) void gated_minmax_kernel(const float* __restrict__ x,
                                                           const float* __restrict__ s,
                                                           const int* __restrict__ lo_tab,
                                                           const float* __restrict__ w_tab,
                                                           unsigned* __restrict__ mm) {
    __shared__ float ls[128];
    __shared__ int llo[64];
    __shared__ float lwt[64];
    __shared__ float red[8];
    const int t = threadIdx.x, lane = t & 63, wave = t >> 6;
    if (t < 128) ls[t] = s[t];
    if (t < 64) { llo[t] = lo_tab[t]; lwt[t] = w_tab[t]; }
    __syncthreads();
    const int wbase = (lane & 15) * 4;
    const int wl0 = llo[wbase + 0], wl1 = llo[wbase + 1], wl2 = llo[wbase + 2], wl3 = llo[wbase + 3];
    const int wh0 = min(wl0 + 1, 3), wh1 = min(wl1 + 1, 3), wh2 = min(wl2 + 1, 3), wh3 = min(wl3 + 1, 3);
    const float fw0 = lwt[wbase + 0], fw1 = lwt[wbase + 1], fw2 = lwt[wbase + 2], fw3 = lwt[wbase + 3];
    const float4* x4 = (const float4*)x;
    float vmin = INFINITY, vmax = -INFINITY;
    #pragma unroll 4
    for (int i = blockIdx.x * 256 + t; i < 8388608; i += gridDim.x * 256) {
        float p0, p1, p2, p3;
        COMPUTE_PRODUCTS(i, p0, p1, p2, p3);
        vmin = fminf(vmin, fminf(fminf(p0, p1), fminf(p2, p3)));
        vmax = fmaxf(vmax, fmaxf(fmaxf(p0, p1), fmaxf(p2, p3)));
    }
    #pragma unroll
    for (int m = 1; m <= 32; m <<= 1) {
        vmin = fminf(vmin, __shfl_xor(vmin, m));
        vmax = fmaxf(vmax, __shfl_xor(vmax, m));
    }
    if ((t & 63) == 0) { red[wave] = vmin; red[4 + wave] = vmax; }
    __syncthreads();
    if (t == 0) {
        float m0 = fminf(fminf(red[0], red[1]), fminf(red[2], red[3]));
        float M0 = fmaxf(fmaxf(red[4], red[5]), fmaxf(red[6], red[7]));
        atomicMin(&mm[0], mapf(m0));
        atomicMax(&mm[1], mapf(M0));
    }
}

__global__ __launch_bounds__(256) void gated_hist_kernel(const float* __restrict__ x,
                                                         const float* __restrict__ s,
                                                         const int* __restrict__ lo_tab,
                                                         const float* __restrict__ w_tab,
                                                         const unsigned* __restrict__ mm,
                                                         unsigned* __restrict__ ghist) {
    __shared__ float ls[128];
    __shared__ int llo[64];
    __shared__ float lwt[64];
    __shared__ unsigned lh[BINS];
    const int t = threadIdx.x, lane = t & 63;
    if (t < 128) ls[t] = s[t];
    if (t < 64) { llo[t] = lo_tab[t]; lwt[t] = w_tab[t]; }
    if (t < BINS) lh[t] = 0u;
    __syncthreads();
    const int wbase = (lane & 15) * 4;
    const int wl0 = llo[wbase + 0], wl1 = llo[wbase + 1], wl2 = llo[wbase + 2], wl3 = llo[wbase + 3];
    const int wh0 = min(wl0 + 1, 3), wh1 = min(wl1 + 1, 3), wh2 = min(wl2 + 1, 3), wh3 = min(wl3 + 1, 3);
    const float fw0 = lwt[wbase + 0], fw1 = lwt[wbase + 1], fw2 = lwt[wbase + 2], fw3 = lwt[wbase + 3];
    const float vmin = unmapf(mm[0]);
    const float vmax = unmapf(mm[1]);
    const float inv = 128.0f / (vmax - vmin + 1e-8f);
    const float4* x4 = (const float4*)x;
    #pragma unroll 4
    for (int i = blockIdx.x * 256 + t; i < 8388608; i += gridDim.x * 256) {
        float p0, p1, p2, p3;
        COMPUTE_PRODUCTS(i, p0, p1, p2, p3);
        int i0 = (int)floorf((p0 - vmin) * inv);
        int i1 = (int)floorf((p1 - vmin) * inv);
        int i2 = (int)floorf((p2 - vmin) * inv);
        int i3 = (int)floorf((p3 - vmin) * inv);
        i0 = min(max(i0, 0), BINS - 1);
        i1 = min(max(i1, 0), BINS - 1);
        i2 = min(max(i2, 0), BINS - 1);
        i3 = min(max(i3, 0), BINS - 1);
        unsigned a0 = 1u + (i1 == i0) + (i2 == i0) + (i3 == i0);
        atomicAdd(&lh[i0], a0);
        if (i1 != i0) atomicAdd(&lh[i1], 1u + (i2 == i1) + (i3 == i1));
        if (i2 != i0 && i2 != i1) atomicAdd(&lh[i2], 1u + (i3 == i2));
        if (i3 != i0 && i3 != i1 && i3 != i2) atomicAdd(&lh[i3], 1u);
    }
    __syncthreads();
    if (t < BINS) {
        unsigned c = lh[t];
        if (c) atomicAdd(&ghist[t], c);
    }
}

__global__ __launch_bounds__(64) void entropy_kernel(const unsigned* __restrict__ ghist,
                                                     float* __restrict__ out) {
    const int t = threadIdx.x;
    float c0 = (float)ghist[t];
    float c1 = (float)ghist[t + 64];
    float s = c0 + c1;
    #pragma unroll
    for (int m = 1; m <= 32; m <<= 1) s += __shfl_xor(s, m);
    const float inv = 1.0f / (s + 1e-10f);
    float p0 = c0 * inv, p1 = c1 * inv;
    float e = p0 * log2f(p0 + 1e-10f) + p1 * log2f(p1 + 1e-10f);
    #pragma unroll
    for (int m = 1; m <= 32; m <<= 1) e += __shfl_xor(e, m);
    if (t == 0) out[0] = -e;
}

extern "C" void kernel_launch(void* const* d_in, const int* in_sizes, int n_in,
                              void* d_out, int out_size, void* d_ws, size_t ws_size,
                              hipStream_t stream) {
    (void)in_sizes; (void)n_in; (void)out_size; (void)ws_size;
    const float* x  = (const float*)d_in[0];
    const float* w1 = (const float*)d_in[1];
    const float* w2 = (const float*)d_in[2];
    float* out = (float*)d_out;
    float* ws  = (float*)d_ws;

    int dev = 0;
    (void)hipGetDevice(&dev);
    int coop = 0;
    (void)hipDeviceGetAttribute(&coop, hipDeviceAttributeCooperativeLaunch, dev);
    int ncu = 0;
    (void)hipDeviceGetAttribute(&ncu, hipDeviceAttributeMultiprocessorCount, dev);
    int maxb = 0;
    (void)hipOccupancyMaxActiveBlocksPerMultiprocessor(&maxb, fused_kernel, 256, 0);

    int G = maxb * ncu;
    if (G > 1024) G = 1024;

    if (coop && G >= 64) {
        void* args[] = {(void*)&x, (void*)&w1, (void*)&w2, (void*)&out, (void*)&ws, (void*)&G};
        hipError_t err = hipLaunchCooperativeKernel((void*)fused_kernel, dim3(G), dim3(256),
                                                    args, 0, stream);
        if (err == hipSuccess) return;
    }

    // ---- fallback: proven multi-kernel path ----
    float* p        = ws;                     // 8192
    float* s        = ws + 8192;              // 128
    int*   lo_tab   = (int*)(ws + 8320);      // 64
    float* w_tab    = ws + 8384;              // 64
    unsigned* mm    = (unsigned*)(ws + 8448); // 2
    unsigned* hist  = (unsigned*)(ws + 8456); // 128

    pool_kernel<<<512, 256, 0, stream>>>(x, p);
    mid_kernel<<<1, 1024, 0, stream>>>(p, w1, w2, s, lo_tab, w_tab, mm, hist);
    gated_minmax_kernel<<<2048, 256, 0, stream>>>(x, s, lo_tab, w_tab, mm);
    gated_hist_kernel<<<2048, 256, 0, stream>>>(x, s, lo_tab, w_tab, mm, hist);
    entropy_kernel<<<1, 64, 0, stream>>>(hist, out);
}

// Round 5
// 159.720 us; speedup vs baseline: 1.9156x; 1.9156x over previous
//
#include <hip/hip_runtime.h>
#include <math.h>

#define BINS 128

// ---------------- ws layout (float units) ----------------
// [0, 8192)        p       pooled means (B=2, C=64, sp=64)
// [8192, 8320)     s       sigmoid gate (2, 64)
// [8320, 8384)     lo_tab  int[64]
// [8384, 8448)     w_tab   float[64]
// [8448, 8450)     mm      mapped uints {min, max}
// [8456, 8584)     hist    uint[128]

__device__ __forceinline__ unsigned mapf(float f) {
    unsigned u = __float_as_uint(f);
    return (u & 0x80000000u) ? ~u : (u | 0x80000000u);
}
__device__ __forceinline__ float unmapf(unsigned m) {
    unsigned u = (m & 0x80000000u) ? (m & 0x7FFFFFFFu) : ~m;
    return __uint_as_float(u);
}
__device__ __forceinline__ float sel4(float g0, float g1, float g2, float g3, int k) {
    float a = (k & 1) ? g1 : g0;
    float b = (k & 1) ? g3 : g2;
    return (k & 2) ? b : a;
}

// Inline trilinear gate recompute (verified exact in R4).
#define COMPUTE_PRODUCTS(i, p0, p1, p2, p3)                                           \
    {                                                                                 \
        float4 xv = x4[i];                                                            \
        const int h6 = ((i) >> 4) & 63;                                               \
        const int d6 = ((i) >> 10) & 63;                                              \
        const int bb = (i) >> 22;                                                     \
        const int hl = llo[h6], dl = llo[d6];                                         \
        const float fh = lwt[h6], fd = lwt[d6];                                       \
        const int hh = min(hl + 1, 3), dh = min(dl + 1, 3);                           \
        const float* sb = ls + bb * 64;                                               \
        const float w00 = (1.f - fd) * (1.f - fh), w01 = (1.f - fd) * fh;             \
        const float w10 = fd * (1.f - fh), w11 = fd * fh;                             \
        const int i00 = dl * 16 + hl * 4, i01 = dl * 16 + hh * 4;                     \
        const int i10 = dh * 16 + hl * 4, i11 = dh * 16 + hh * 4;                     \
        const float g0 = w00 * sb[i00 + 0] + w01 * sb[i01 + 0] + w10 * sb[i10 + 0] + w11 * sb[i11 + 0]; \
        const float g1 = w00 * sb[i00 + 1] + w01 * sb[i01 + 1] + w10 * sb[i10 + 1] + w11 * sb[i11 + 1]; \
        const float g2 = w00 * sb[i00 + 2] + w01 * sb[i01 + 2] + w10 * sb[i10 + 2] + w11 * sb[i11 + 2]; \
        const float g3 = w00 * sb[i00 + 3] + w01 * sb[i01 + 3] + w10 * sb[i10 + 3] + w11 * sb[i11 + 3]; \
        float glo, ghi, sv;                                                           \
        glo = sel4(g0, g1, g2, g3, wl0); ghi = sel4(g0, g1, g2, g3, wh0);             \
        sv = glo + fw0 * (ghi - glo); p0 = xv.x * sv;                                 \
        glo = sel4(g0, g1, g2, g3, wl1); ghi = sel4(g0, g1, g2, g3, wh1);             \
        sv = glo + fw1 * (ghi - glo); p1 = xv.y * sv;                                 \
        glo = sel4(g0, g1, g2, g3, wl2); ghi = sel4(g0, g1, g2, g3, wh2);             \
        sv = glo + fw2 * (ghi - glo); p2 = xv.z * sv;                                 \
        glo = sel4(g0, g1, g2, g3, wl3); ghi = sel4(g0, g1, g2, g3, wh3);             \
        sv = glo + fw3 * (ghi - glo); p3 = xv.w * sv;                                 \
    }

// ---- K1: adaptive avg pool 16^3 block means (512 blocks, one 16x64x64 slab each) ----
__global__ __launch_bounds__(256) void pool_kernel(const float* __restrict__ x,
                                                   float* __restrict__ p) {
    const int blk = blockIdx.x;
    const int t = threadIdx.x;
    const float4* xb = (const float4*)x + (size_t)blk * 16384;
    float acc0 = 0.f, acc1 = 0.f, acc2 = 0.f, acc3 = 0.f;
    for (int n = 0; n < 64; n += 4) {
        float4 v0 = xb[(n + 0) * 256 + t]; acc0 += (v0.x + v0.y) + (v0.z + v0.w);
        float4 v1 = xb[(n + 1) * 256 + t]; acc1 += (v1.x + v1.y) + (v1.z + v1.w);
        float4 v2 = xb[(n + 2) * 256 + t]; acc2 += (v2.x + v2.y) + (v2.z + v2.w);
        float4 v3 = xb[(n + 3) * 256 + t]; acc3 += (v3.x + v3.y) + (v3.z + v3.w);
    }
    #pragma unroll
    for (int m = 0; m < 4; ++m) {
        int mask = (m == 0) ? 1 : (m == 1) ? 2 : (m == 2) ? 16 : 32;
        acc0 += __shfl_xor(acc0, mask);
        acc1 += __shfl_xor(acc1, mask);
        acc2 += __shfl_xor(acc2, mask);
        acc3 += __shfl_xor(acc3, mask);
    }
    __shared__ float red[64];
    const int lane = t & 63, wave = t >> 6;
    if (lane < 16 && (lane & 3) == 0) {
        const int pw = lane >> 2;
        red[(0 * 4 + pw) * 4 + wave] = acc0;
        red[(1 * 4 + pw) * 4 + wave] = acc1;
        red[(2 * 4 + pw) * 4 + wave] = acc2;
        red[(3 * 4 + pw) * 4 + wave] = acc3;
    }
    __syncthreads();
    if (t < 16)
        p[blk * 16 + t] = (red[t * 4 + 0] + red[t * 4 + 1] + red[t * 4 + 2] + red[t * 4 + 3]) * (1.0f / 4096.0f);
}

// ---- K2: w1 conv + InstanceNorm + GELU + w2 conv + sigmoid + tables + init ----
__global__ __launch_bounds__(1024) void mid_kernel(const float* __restrict__ p,
                                                   const float* __restrict__ w1,
                                                   const float* __restrict__ w2,
                                                   float* __restrict__ s_out,
                                                   int* __restrict__ lo_tab,
                                                   float* __restrict__ w_tab,
                                                   unsigned* __restrict__ mm,
                                                   unsigned* __restrict__ hist) {
    __shared__ float hs[2 * 8 * 64];
    const int t = threadIdx.x;
    const int b = t >> 9, cm = (t >> 6) & 7, sp = t & 63;
    float h = 0.f;
    const float* pb = p + b * 64 * 64 + sp;
    const float* w1r = w1 + cm * 64;
    for (int c = 0; c < 64; ++c) h += w1r[c] * pb[c * 64];
    float s1 = h;
    #pragma unroll
    for (int m = 1; m <= 32; m <<= 1) s1 += __shfl_xor(s1, m);
    const float mu = s1 * (1.0f / 64.0f);
    float d = h - mu;
    float s2 = d * d;
    #pragma unroll
    for (int m = 1; m <= 32; m <<= 1) s2 += __shfl_xor(s2, m);
    const float var = s2 * (1.0f / 64.0f);
    const float hn = d / sqrtf(var + 1e-5f);
    hs[(b * 8 + cm) * 64 + sp] = 0.5f * hn * (1.0f + erff(hn * 0.70710678118654752440f));
    __syncthreads();
    if (t < 128) {
        const int bb = t >> 6, ss = t & 63;
        float acc = 0.f;
        #pragma unroll
        for (int c = 0; c < 8; ++c) acc += w2[c] * hs[(bb * 8 + c) * 64 + ss];
        s_out[t] = 1.0f / (1.0f + expf(-acc));
    }
    if (t < 64) {
        float coord = ((float)t + 0.5f) * 0.0625f - 0.5f;
        coord = fminf(fmaxf(coord, 0.0f), 3.0f);
        int lo = (int)floorf(coord);
        lo_tab[t] = lo;
        w_tab[t] = coord - (float)lo;
    }
    if (t == 0) { mm[0] = 0xFFFFFFFFu; mm[1] = 0u; }
    if (t >= 128 && t < 256) hist[t - 128] = 0u;
}

// ---- K3: global min/max of x * gate (gate recomputed inline) ----
__global__ __launch_bounds__(256) void gated_minmax_kernel(const float* __restrict__ x,
                                                           const float* __restrict__ s,
                                                           const int* __restrict__ lo_tab,
                                                           const float* __restrict__ w_tab,
                                                           unsigned* __restrict__ mm) {
    __shared__ float ls[128];
    __shared__ int llo[64];
    __shared__ float lwt[64];
    __shared__ float red[8];
    const int t = threadIdx.x, lane = t & 63, wave = t >> 6;
    if (t < 128) ls[t] = s[t];
    if (t < 64) { llo[t] = lo_tab[t]; lwt[t] = w_tab[t]; }
    __syncthreads();
    const int wbase = (lane & 15) * 4;
    const int wl0 = llo[wbase + 0], wl1 = llo[wbase + 1], wl2 = llo[wbase + 2], wl3 = llo[wbase + 3];
    const int wh0 = min(wl0 + 1, 3), wh1 = min(wl1 + 1, 3), wh2 = min(wl2 + 1, 3), wh3 = min(wl3 + 1, 3);
    const float fw0 = lwt[wbase + 0], fw1 = lwt[wbase + 1], fw2 = lwt[wbase + 2], fw3 = lwt[wbase + 3];
    const float4* x4 = (const float4*)x;
    float vmin = INFINITY, vmax = -INFINITY;
    #pragma unroll 4
    for (int i = blockIdx.x * 256 + t; i < 8388608; i += gridDim.x * 256) {
        float p0, p1, p2, p3;
        COMPUTE_PRODUCTS(i, p0, p1, p2, p3);
        vmin = fminf(vmin, fminf(fminf(p0, p1), fminf(p2, p3)));
        vmax = fmaxf(vmax, fmaxf(fmaxf(p0, p1), fmaxf(p2, p3)));
    }
    #pragma unroll
    for (int m = 1; m <= 32; m <<= 1) {
        vmin = fminf(vmin, __shfl_xor(vmin, m));
        vmax = fmaxf(vmax, __shfl_xor(vmax, m));
    }
    if ((t & 63) == 0) { red[wave] = vmin; red[4 + wave] = vmax; }
    __syncthreads();
    if (t == 0) {
        float m0 = fminf(fminf(red[0], red[1]), fminf(red[2], red[3]));
        float M0 = fmaxf(fmaxf(red[4], red[5]), fmaxf(red[6], red[7]));
        atomicMin(&mm[0], mapf(m0));
        atomicMax(&mm[1], mapf(M0));
    }
}

// ---- K4: 128-bin histogram of normalized x * gate ----
__global__ __launch_bounds__(256) void gated_hist_kernel(const float* __restrict__ x,
                                                         const float* __restrict__ s,
                                                         const int* __restrict__ lo_tab,
                                                         const float* __restrict__ w_tab,
                                                         const unsigned* __restrict__ mm,
                                                         unsigned* __restrict__ ghist) {
    __shared__ float ls[128];
    __shared__ int llo[64];
    __shared__ float lwt[64];
    __shared__ unsigned lh[BINS];
    const int t = threadIdx.x, lane = t & 63;
    if (t < 128) ls[t] = s[t];
    if (t < 64) { llo[t] = lo_tab[t]; lwt[t] = w_tab[t]; }
    if (t < BINS) lh[t] = 0u;
    __syncthreads();
    const int wbase = (lane & 15) * 4;
    const int wl0 = llo[wbase + 0], wl1 = llo[wbase + 1], wl2 = llo[wbase + 2], wl3 = llo[wbase + 3];
    const int wh0 = min(wl0 + 1, 3), wh1 = min(wl1 + 1, 3), wh2 = min(wl2 + 1, 3), wh3 = min(wl3 + 1, 3);
    const float fw0 = lwt[wbase + 0], fw1 = lwt[wbase + 1], fw2 = lwt[wbase + 2], fw3 = lwt[wbase + 3];
    const float vmin = unmapf(mm[0]);
    const float vmax = unmapf(mm[1]);
    const float inv = 128.0f / (vmax - vmin + 1e-8f);
    const float4* x4 = (const float4*)x;
    #pragma unroll 4
    for (int i = blockIdx.x * 256 + t; i < 8388608; i += gridDim.x * 256) {
        float p0, p1, p2, p3;
        COMPUTE_PRODUCTS(i, p0, p1, p2, p3);
        int i0 = (int)floorf((p0 - vmin) * inv);
        int i1 = (int)floorf((p1 - vmin) * inv);
        int i2 = (int)floorf((p2 - vmin) * inv);
        int i3 = (int)floorf((p3 - vmin) * inv);
        i0 = min(max(i0, 0), BINS - 1);
        i1 = min(max(i1, 0), BINS - 1);
        i2 = min(max(i2, 0), BINS - 1);
        i3 = min(max(i3, 0), BINS - 1);
        unsigned a0 = 1u + (i1 == i0) + (i2 == i0) + (i3 == i0);
        atomicAdd(&lh[i0], a0);
        if (i1 != i0) atomicAdd(&lh[i1], 1u + (i2 == i1) + (i3 == i1));
        if (i2 != i0 && i2 != i1) atomicAdd(&lh[i2], 1u + (i3 == i2));
        if (i3 != i0 && i3 != i1 && i3 != i2) atomicAdd(&lh[i3], 1u);
    }
    __syncthreads();
    if (t < BINS) {
        unsigned c = lh[t];
        if (c) atomicAdd(&ghist[t], c);
    }
}

// ---- K5: entropy ----
__global__ __launch_bounds__(64) void entropy_kernel(const unsigned* __restrict__ ghist,
                                                     float* __restrict__ out) {
    const int t = threadIdx.x;
    float c0 = (float)ghist[t];
    float c1 = (float)ghist[t + 64];
    float s = c0 + c1;
    #pragma unroll
    for (int m = 1; m <= 32; m <<= 1) s += __shfl_xor(s, m);
    const float inv = 1.0f / (s + 1e-10f);
    float p0 = c0 * inv, p1 = c1 * inv;
    float e = p0 * log2f(p0 + 1e-10f) + p1 * log2f(p1 + 1e-10f);
    #pragma unroll
    for (int m = 1; m <= 32; m <<= 1) e += __shfl_xor(e, m);
    if (t == 0) out[0] = -e;
}

extern "C" void kernel_launch(void* const* d_in, const int* in_sizes, int n_in,
                              void* d_out, int out_size, void* d_ws, size_t ws_size,
                              hipStream_t stream) {
    (void)in_sizes; (void)n_in; (void)out_size; (void)ws_size;
    const float* x  = (const float*)d_in[0];
    const float* w1 = (const float*)d_in[1];
    const float* w2 = (const float*)d_in[2];
    float* out = (float*)d_out;
    float* ws  = (float*)d_ws;

    float* p        = ws;                     // 8192
    float* s        = ws + 8192;              // 128
    int*   lo_tab   = (int*)(ws + 8320);      // 64
    float* w_tab    = ws + 8384;              // 64
    unsigned* mm    = (unsigned*)(ws + 8448); // 2
    unsigned* hist  = (unsigned*)(ws + 8456); // 128

    pool_kernel<<<512, 256, 0, stream>>>(x, p);
    mid_kernel<<<1, 1024, 0, stream>>>(p, w1, w2, s, lo_tab, w_tab, mm, hist);
    gated_minmax_kernel<<<2048, 256, 0, stream>>>(x, s, lo_tab, w_tab, mm);
    gated_hist_kernel<<<2048, 256, 0, stream>>>(x, s, lo_tab, w_tab, mm, hist);
    entropy_kernel<<<1, 64, 0, stream>>>(hist, out);
}

// Round 6
// 158.404 us; speedup vs baseline: 1.9316x; 1.0083x over previous
//
#include <hip/hip_runtime.h>
#include <math.h>

#define BINS 128

// ---------------- ws layout (float units) ----------------
// [0, 16384)       pp      pool partials [sb=(b*64+c)*8+part][16 cells]
// [16384, 16512)   s       sigmoid gate (2, 64)
// [16512, 16576)   lo_tab  int[64]
// [16576, 16640)   w_tab   float[64]
// [16640, 16642)   mm      mapped uints {min, max}
// [16648, 16776)   hist    uint[128]

__device__ __forceinline__ unsigned mapf(float f) {
    unsigned u = __float_as_uint(f);
    return (u & 0x80000000u) ? ~u : (u | 0x80000000u);
}
__device__ __forceinline__ float unmapf(unsigned m) {
    unsigned u = (m & 0x80000000u) ? (m & 0x7FFFFFFFu) : ~m;
    return __uint_as_float(u);
}
__device__ __forceinline__ float sel4(float g0, float g1, float g2, float g3, int k) {
    float a = (k & 1) ? g1 : g0;
    float b = (k & 1) ? g3 : g2;
    return (k & 2) ? b : a;
}

// ---- K1: pool partials. 1024 blocks; block sb covers 8 d-slices of slab (b,c). ----
__global__ __launch_bounds__(256) void pool_kernel(const float* __restrict__ x,
                                                   float* __restrict__ pp) {
    const int sb = blockIdx.x;
    const int t = threadIdx.x;
    const float4* xb = (const float4*)x + (size_t)sb * 8192;
    float a0 = 0.f, a1 = 0.f, a2 = 0.f, a3 = 0.f;
    #pragma unroll 2
    for (int n = 0; n < 32; n += 4) {
        float4 v0 = xb[(n + 0) * 256 + t]; a0 += (v0.x + v0.y) + (v0.z + v0.w);
        float4 v1 = xb[(n + 1) * 256 + t]; a1 += (v1.x + v1.y) + (v1.z + v1.w);
        float4 v2 = xb[(n + 2) * 256 + t]; a2 += (v2.x + v2.y) + (v2.z + v2.w);
        float4 v3 = xb[(n + 3) * 256 + t]; a3 += (v3.x + v3.y) + (v3.z + v3.w);
    }
    // ph = n&3 -> a0..a3 ; pw = lane bits {2,3} ; reduce lane bits {0,1,4,5}
    #pragma unroll
    for (int m = 0; m < 4; ++m) {
        const int msk = (m == 0) ? 1 : (m == 1) ? 2 : (m == 2) ? 16 : 32;
        a0 += __shfl_xor(a0, msk); a1 += __shfl_xor(a1, msk);
        a2 += __shfl_xor(a2, msk); a3 += __shfl_xor(a3, msk);
    }
    __shared__ float red[64];
    const int lane = t & 63, wave = t >> 6;
    if (lane < 16 && (lane & 3) == 0) {
        const int pw = lane >> 2;
        red[(0 * 4 + pw) * 4 + wave] = a0;
        red[(1 * 4 + pw) * 4 + wave] = a1;
        red[(2 * 4 + pw) * 4 + wave] = a2;
        red[(3 * 4 + pw) * 4 + wave] = a3;
    }
    __syncthreads();
    if (t < 16)
        pp[sb * 16 + t] = red[t * 4 + 0] + red[t * 4 + 1] + red[t * 4 + 2] + red[t * 4 + 3];
}

// ---- K2: w1 conv (from partials) + InstanceNorm + GELU + w2 conv + sigmoid + tables ----
__global__ __launch_bounds__(1024) void mid_kernel(const float* __restrict__ pp,
                                                   const float* __restrict__ w1,
                                                   const float* __restrict__ w2,
                                                   float* __restrict__ s_out,
                                                   int* __restrict__ lo_tab,
                                                   float* __restrict__ w_tab,
                                                   unsigned* __restrict__ mm,
                                                   unsigned* __restrict__ hist) {
    __shared__ float hs[2 * 8 * 64];
    const int t = threadIdx.x;
    const int b = t >> 9, cm = (t >> 6) & 7, sp = t & 63;
    const int off = (sp >> 4) * 32 + (sp & 15);   // part=2*pd -> pd*32 + cell
    const float* w1r = w1 + cm * 64;
    const float* ppb = pp + b * 64 * 128;
    float h = 0.f;
    for (int c = 0; c < 64; ++c)
        h += w1r[c] * (ppb[c * 128 + off] + ppb[c * 128 + 16 + off]);
    h *= (1.0f / 4096.0f);

    float s1 = h;
    #pragma unroll
    for (int m = 1; m <= 32; m <<= 1) s1 += __shfl_xor(s1, m);
    const float mu = s1 * (1.0f / 64.0f);
    float d = h - mu;
    float s2 = d * d;
    #pragma unroll
    for (int m = 1; m <= 32; m <<= 1) s2 += __shfl_xor(s2, m);
    const float var = s2 * (1.0f / 64.0f);
    const float hn = d / sqrtf(var + 1e-5f);
    hs[(b * 8 + cm) * 64 + sp] = 0.5f * hn * (1.0f + erff(hn * 0.70710678118654752440f));
    __syncthreads();
    if (t < 128) {
        const int bb = t >> 6, ss = t & 63;
        float acc = 0.f;
        #pragma unroll
        for (int c = 0; c < 8; ++c) acc += w2[c] * hs[(bb * 8 + c) * 64 + ss];
        s_out[t] = 1.0f / (1.0f + expf(-acc));
    }
    if (t < 64) {
        float coord = ((float)t + 0.5f) * 0.0625f - 0.5f;
        coord = fminf(fmaxf(coord, 0.0f), 3.0f);
        int lo = (int)floorf(coord);
        lo_tab[t] = lo;
        w_tab[t] = coord - (float)lo;
    }
    if (t == 0) { mm[0] = 0xFFFFFFFFu; mm[1] = 0u; }
    if (t >= 128 && t < 256) hist[t - 128] = 0u;
}

// Per-thread gate precompute: with grid 2048x256, stride = 2^19 float4, so
// h6/d6 (bits 4-9 / 10-15 of i) are loop-invariant and b = (k>=8).
// Produces 8 registers: gate at this thread's 4 w-positions for b=0 and b=1.
#define PRECOMPUTE_GATES(base)                                                        \
    const int h6 = ((base) >> 4) & 63;                                                \
    const int d6 = ((base) >> 10) & 63;                                               \
    const int hl = llo[h6], dl = llo[d6];                                             \
    const float fh = lwt[h6], fd = lwt[d6];                                           \
    const int hh = min(hl + 1, 3), dh = min(dl + 1, 3);                               \
    const float w00 = (1.f - fd) * (1.f - fh), w01 = (1.f - fd) * fh;                 \
    const float w10 = fd * (1.f - fh), w11 = fd * fh;                                 \
    const int i00 = dl * 16 + hl * 4, i01 = dl * 16 + hh * 4;                         \
    const int i10 = dh * 16 + hl * 4, i11 = dh * 16 + hh * 4;                         \
    const int wbase = (t & 15) * 4;                                                   \
    const int wl0 = llo[wbase + 0], wl1 = llo[wbase + 1], wl2 = llo[wbase + 2], wl3 = llo[wbase + 3]; \
    const int wh0 = min(wl0 + 1, 3), wh1 = min(wl1 + 1, 3), wh2 = min(wl2 + 1, 3), wh3 = min(wl3 + 1, 3); \
    const float fw0 = lwt[wbase + 0], fw1 = lwt[wbase + 1], fw2 = lwt[wbase + 2], fw3 = lwt[wbase + 3]; \
    float a00, a01, a02, a03, a10, a11, a12, a13;                                     \
    {                                                                                 \
        const float* sb0 = ls;                                                        \
        float g0 = w00 * sb0[i00 + 0] + w01 * sb0[i01 + 0] + w10 * sb0[i10 + 0] + w11 * sb0[i11 + 0]; \
        float g1 = w00 * sb0[i00 + 1] + w01 * sb0[i01 + 1] + w10 * sb0[i10 + 1] + w11 * sb0[i11 + 1]; \
        float g2 = w00 * sb0[i00 + 2] + w01 * sb0[i01 + 2] + w10 * sb0[i10 + 2] + w11 * sb0[i11 + 2]; \
        float g3 = w00 * sb0[i00 + 3] + w01 * sb0[i01 + 3] + w10 * sb0[i10 + 3] + w11 * sb0[i11 + 3]; \
        float lo, hi;                                                                 \
        lo = sel4(g0, g1, g2, g3, wl0); hi = sel4(g0, g1, g2, g3, wh0); a00 = lo + fw0 * (hi - lo); \
        lo = sel4(g0, g1, g2, g3, wl1); hi = sel4(g0, g1, g2, g3, wh1); a01 = lo + fw1 * (hi - lo); \
        lo = sel4(g0, g1, g2, g3, wl2); hi = sel4(g0, g1, g2, g3, wh2); a02 = lo + fw2 * (hi - lo); \
        lo = sel4(g0, g1, g2, g3, wl3); hi = sel4(g0, g1, g2, g3, wh3); a03 = lo + fw3 * (hi - lo); \
        const float* sb1 = ls + 64;                                                   \
        g0 = w00 * sb1[i00 + 0] + w01 * sb1[i01 + 0] + w10 * sb1[i10 + 0] + w11 * sb1[i11 + 0]; \
        g1 = w00 * sb1[i00 + 1] + w01 * sb1[i01 + 1] + w10 * sb1[i10 + 1] + w11 * sb1[i11 + 1]; \
        g2 = w00 * sb1[i00 + 2] + w01 * sb1[i01 + 2] + w10 * sb1[i10 + 2] + w11 * sb1[i11 + 2]; \
        g3 = w00 * sb1[i00 + 3] + w01 * sb1[i01 + 3] + w10 * sb1[i10 + 3] + w11 * sb1[i11 + 3]; \
        lo = sel4(g0, g1, g2, g3, wl0); hi = sel4(g0, g1, g2, g3, wh0); a10 = lo + fw0 * (hi - lo); \
        lo = sel4(g0, g1, g2, g3, wl1); hi = sel4(g0, g1, g2, g3, wh1); a11 = lo + fw1 * (hi - lo); \
        lo = sel4(g0, g1, g2, g3, wl2); hi = sel4(g0, g1, g2, g3, wh2); a12 = lo + fw2 * (hi - lo); \
        lo = sel4(g0, g1, g2, g3, wl3); hi = sel4(g0, g1, g2, g3, wh3); a13 = lo + fw3 * (hi - lo); \
    }

// ---- K3: global min/max of x * gate. MUST launch with <<<2048, 256>>>. ----
__global__ __launch_bounds__(256) void gated_minmax_kernel(const float* __restrict__ x,
                                                           const float* __restrict__ s,
                                                           const int* __restrict__ lo_tab,
                                                           const float* __restrict__ w_tab,
                                                           unsigned* __restrict__ mm) {
    __shared__ float ls[128];
    __shared__ int llo[64];
    __shared__ float lwt[64];
    __shared__ float red[8];
    const int t = threadIdx.x;
    if (t < 128) ls[t] = s[t];
    if (t < 64) { llo[t] = lo_tab[t]; lwt[t] = w_tab[t]; }
    __syncthreads();

    const int base = blockIdx.x * 256 + t;   // < 2^19
    PRECOMPUTE_GATES(base);

    const float4* xp = (const float4*)x + base;
    float vmin = INFINITY, vmax = -INFINITY;
    #pragma unroll
    for (int k = 0; k < 8; ++k) {
        float4 xv = xp[k * 524288];
        float p0 = xv.x * a00, p1 = xv.y * a01, p2 = xv.z * a02, p3 = xv.w * a03;
        vmin = fminf(vmin, fminf(fminf(p0, p1), fminf(p2, p3)));
        vmax = fmaxf(vmax, fmaxf(fmaxf(p0, p1), fmaxf(p2, p3)));
    }
    #pragma unroll
    for (int k = 8; k < 16; ++k) {
        float4 xv = xp[k * 524288];
        float p0 = xv.x * a10, p1 = xv.y * a11, p2 = xv.z * a12, p3 = xv.w * a13;
        vmin = fminf(vmin, fminf(fminf(p0, p1), fminf(p2, p3)));
        vmax = fmaxf(vmax, fmaxf(fmaxf(p0, p1), fmaxf(p2, p3)));
    }
    #pragma unroll
    for (int m = 1; m <= 32; m <<= 1) {
        vmin = fminf(vmin, __shfl_xor(vmin, m));
        vmax = fmaxf(vmax, __shfl_xor(vmax, m));
    }
    const int wave = t >> 6;
    if ((t & 63) == 0) { red[wave] = vmin; red[4 + wave] = vmax; }
    __syncthreads();
    if (t == 0) {
        float m0 = fminf(fminf(red[0], red[1]), fminf(red[2], red[3]));
        float M0 = fmaxf(fmaxf(red[4], red[5]), fmaxf(red[6], red[7]));
        atomicMin(&mm[0], mapf(m0));
        atomicMax(&mm[1], mapf(M0));
    }
}

// ---- K4: 128-bin histogram. MUST launch with <<<2048, 256>>>. ----
__global__ __launch_bounds__(256) void gated_hist_kernel(const float* __restrict__ x,
                                                         const float* __restrict__ s,
                                                         const int* __restrict__ lo_tab,
                                                         const float* __restrict__ w_tab,
                                                         const unsigned* __restrict__ mm,
                                                         unsigned* __restrict__ ghist) {
    __shared__ float ls[128];
    __shared__ int llo[64];
    __shared__ float lwt[64];
    __shared__ unsigned lh[BINS];
    const int t = threadIdx.x;
    if (t < 128) ls[t] = s[t];
    if (t < 64) { llo[t] = lo_tab[t]; lwt[t] = w_tab[t]; }
    if (t < BINS) lh[t] = 0u;
    __syncthreads();

    const int base = blockIdx.x * 256 + t;
    PRECOMPUTE_GATES(base);

    const float vmin = unmapf(mm[0]);
    const float vmax = unmapf(mm[1]);
    const float inv = 128.0f / (vmax - vmin + 1e-8f);
    const float4* xp = (const float4*)x + base;

#define HIST4(xv, b0, b1, b2, b3)                                   \
    {                                                               \
        float p0 = xv.x * b0, p1 = xv.y * b1, p2 = xv.z * b2, p3 = xv.w * b3; \
        int i0 = (int)floorf((p0 - vmin) * inv);                    \
        int i1 = (int)floorf((p1 - vmin) * inv);                    \
        int i2 = (int)floorf((p2 - vmin) * inv);                    \
        int i3 = (int)floorf((p3 - vmin) * inv);                    \
        i0 = min(max(i0, 0), BINS - 1);                             \
        i1 = min(max(i1, 0), BINS - 1);                             \
        i2 = min(max(i2, 0), BINS - 1);                             \
        i3 = min(max(i3, 0), BINS - 1);                             \
        atomicAdd(&lh[i0], 1u);                                     \
        atomicAdd(&lh[i1], 1u);                                     \
        atomicAdd(&lh[i2], 1u);                                     \
        atomicAdd(&lh[i3], 1u);                                     \
    }

    #pragma unroll
    for (int k = 0; k < 8; ++k) {
        float4 xv = xp[k * 524288];
        HIST4(xv, a00, a01, a02, a03);
    }
    #pragma unroll
    for (int k = 8; k < 16; ++k) {
        float4 xv = xp[k * 524288];
        HIST4(xv, a10, a11, a12, a13);
    }
#undef HIST4

    __syncthreads();
    if (t < BINS) {
        unsigned c = lh[t];
        if (c) atomicAdd(&ghist[t], c);
    }
}

// ---- K5: entropy ----
__global__ __launch_bounds__(64) void entropy_kernel(const unsigned* __restrict__ ghist,
                                                     float* __restrict__ out) {
    const int t = threadIdx.x;
    float c0 = (float)ghist[t];
    float c1 = (float)ghist[t + 64];
    float s = c0 + c1;
    #pragma unroll
    for (int m = 1; m <= 32; m <<= 1) s += __shfl_xor(s, m);
    const float inv = 1.0f / (s + 1e-10f);
    float p0 = c0 * inv, p1 = c1 * inv;
    float e = p0 * log2f(p0 + 1e-10f) + p1 * log2f(p1 + 1e-10f);
    #pragma unroll
    for (int m = 1; m <= 32; m <<= 1) e += __shfl_xor(e, m);
    if (t == 0) out[0] = -e;
}

extern "C" void kernel_launch(void* const* d_in, const int* in_sizes, int n_in,
                              void* d_out, int out_size, void* d_ws, size_t ws_size,
                              hipStream_t stream) {
    (void)in_sizes; (void)n_in; (void)out_size; (void)ws_size;
    const float* x  = (const float*)d_in[0];
    const float* w1 = (const float*)d_in[1];
    const float* w2 = (const float*)d_in[2];
    float* out = (float*)d_out;
    float* ws  = (float*)d_ws;

    float* pp       = ws;                      // 16384
    float* s        = ws + 16384;              // 128
    int*   lo_tab   = (int*)(ws + 16512);      // 64
    float* w_tab    = ws + 16576;              // 64
    unsigned* mm    = (unsigned*)(ws + 16640); // 2
    unsigned* hist  = (unsigned*)(ws + 16648); // 128

    pool_kernel<<<1024, 256, 0, stream>>>(x, pp);
    mid_kernel<<<1, 1024, 0, stream>>>(pp, w1, w2, s, lo_tab, w_tab, mm, hist);
    gated_minmax_kernel<<<2048, 256, 0, stream>>>(x, s, lo_tab, w_tab, mm);
    gated_hist_kernel<<<2048, 256, 0, stream>>>(x, s, lo_tab, w_tab, mm, hist);
    entropy_kernel<<<1, 64, 0, stream>>>(hist, out);
}